// Round 10
// baseline (131.633 us; speedup 1.0000x reference)
//
#include <hip/hip_runtime.h>
#include <hip/hip_bf16.h>
#include <math.h>

#define NQ   9
#define NDIM 256
#define NHID 130
#define NST  512
#define NBATCH 64
#define P_TAYLOR 24
#define THETA 2.0f

__device__ __forceinline__ float softplusf(float x) {
    return (x > 0.f) ? (x + log1pf(expf(-x))) : log1pf(expf(x));
}

// One block per batch element. 512 threads, one per basis state.
// MLP -> pulse params -> sparse H (diag in regs, 9 off-diag couplings),
// then psi = exp(-i t H) e0 via K sub-steps of a degree-24 Taylor
// polynomial; ||dt*H||_inf <= 2 via a closed-form norm bound.
// OUTPUT (decoded R0-R9): d_out is FLOAT32, out_size = 32768 = (64,512):
// the REAL PART of psi only (complex64 reference realified by the harness).
__global__ __launch_bounds__(512) void ryd_kernel(
    const float* __restrict__ x,    const float* __restrict__ mask,
    const float* __restrict__ adj,  const float* __restrict__ W1,
    const float* __restrict__ b1,   const float* __restrict__ W2,
    const float* __restrict__ b2,   float* __restrict__ out)
{
    const int b   = blockIdx.x;
    const int tid = threadIdx.x;

    __shared__ float xs[NDIM];
    __shared__ float hs[NHID];
    __shared__ float vs[4];
    __shared__ float ms[NQ];
    __shared__ float Wm[NQ][NQ];
    __shared__ float prm[4];   // 0:Are 1:Aim 2:delta 3:dt
    __shared__ int   Ksh;
    __shared__ float2 buf[2][NST];

    if (tid < NDIM) xs[tid] = x[b*NDIM + tid];
    if (tid < NQ)   ms[tid] = mask[b*NQ + tid];
    __syncthreads();

    if (tid < NHID) {
        float acc = b1[tid];
        #pragma unroll 8
        for (int i = 0; i < NDIM; ++i) acc = fmaf(xs[i], W1[i*NHID + tid], acc);
        hs[tid] = fmaxf(acc, 0.f);
    }
    __syncthreads();

    if (tid < 4) {
        float acc = b2[tid];
        for (int j = 0; j < NHID; ++j) acc = fmaf(hs[j], W2[j*4 + tid], acc);
        vs[tid] = acc;
    }
    if (tid < NQ*NQ) {
        int i = tid / NQ, j = tid % NQ;
        Wm[i][j] = (866.0f/729.0f) * adj[i*NQ + j] * ms[i] * ms[j];
    }
    __syncthreads();

    if (tid == 0) {
        float omega = softplusf(vs[0]);
        float delta = vs[1];
        float phi   = vs[2];
        float t     = softplusf(vs[3]);
        float halfw = 0.5f * omega;

        float sm = 0.f;
        for (int i = 0; i < NQ; ++i) sm += ms[i];
        float sw = 0.f;
        for (int i = 0; i < NQ; ++i)
            for (int j = 0; j < NQ; ++j) sw += Wm[i][j];
        float Bn = sw + fabsf(delta)*sm + halfw*sm;  // >= ||H||_inf
        float tb = t * Bn;
        int K = (int)ceilf(tb / THETA);
        if (K < 1) K = 1;
        if (K > 200000) K = 200000;
        Ksh = K;
        prm[0] = halfw * cosf(phi);
        prm[1] = halfw * sinf(phi);
        prm[2] = delta;
        prm[3] = t / (float)K;
    }
    __syncthreads();

    const int s = tid;
    const float delta = prm[2];
    float occf[NQ];
    #pragma unroll
    for (int j = 0; j < NQ; ++j) occf[j] = ((s >> (NQ-1-j)) & 1) ? 0.f : 1.f;

    float D = 0.f, mo = 0.f;
    #pragma unroll
    for (int i = 0; i < NQ; ++i) {
        mo = fmaf(ms[i], occf[i], mo);
        float r = 0.f;
        #pragma unroll
        for (int j = 0; j < NQ; ++j) r = fmaf(Wm[i][j], occf[j], r);
        D = fmaf(occf[i], r, D);
    }
    D = fmaf(-delta, mo, D);

    const float Are = prm[0], Aim = prm[1], dt = prm[3];
    const int K = Ksh;

    float cjre[NQ], cjim[NQ];
    int nb[NQ];
    #pragma unroll
    for (int j = 0; j < NQ; ++j) {
        cjre[j] = ms[j] * Are;
        cjim[j] = (occf[j] != 0.f ? 1.f : -1.f) * ms[j] * Aim;
        nb[j]   = s ^ (1 << (NQ-1-j));
    }

    float pre = (s == 0) ? 1.f : 0.f, pim = 0.f;

    for (int step = 0; step < K; ++step) {
        float accre = pre, accim = pim;
        float cre = pre, cim = pim;
        int cb = 0;
        buf[0][s] = make_float2(cre, cim);
        __syncthreads();
        for (int k = 1; k <= P_TAYLOR; ++k) {
            float yre = D * cre, yim = D * cim;
            #pragma unroll
            for (int j = 0; j < NQ; ++j) {
                float2 z = buf[cb][nb[j]];
                yre += cjre[j]*z.x - cjim[j]*z.y;
                yim += cjre[j]*z.y + cjim[j]*z.x;
            }
            float al = dt / (float)k;
            cre =  al * yim;
            cim = -al * yre;
            accre += cre; accim += cim;
            cb ^= 1;
            buf[cb][s] = make_float2(cre, cim);
            __syncthreads();
        }
        pre = accre; pim = accim;
    }

    // FLOAT32 output: real part only, (64, 512) row-major.
    out[b*NST + s] = pre;
}

extern "C" void kernel_launch(void* const* d_in, const int* in_sizes, int n_in,
                              void* d_out, int out_size, void* d_ws, size_t ws_size,
                              hipStream_t stream) {
    // Size-keyed input routing (pairwise-distinct element counts):
    //   x:16384  mask:576  adj:81  W1:33280  b1:130  W2:520  b2:4
    const float *x = nullptr, *msk = nullptr, *adj = nullptr,
                *W1 = nullptr, *b1 = nullptr, *W2 = nullptr, *b2 = nullptr;
    for (int i = 0; i < n_in; ++i) {
        const float* p = (const float*)d_in[i];
        switch (in_sizes[i]) {
            case 16384: x   = p; break;
            case 576:   msk = p; break;
            case 81:    adj = p; break;
            case 33280: W1  = p; break;
            case 130:   b1  = p; break;
            case 520:   W2  = p; break;
            case 4:     b2  = p; break;
            default: break;
        }
    }
    ryd_kernel<<<NBATCH, NST, 0, stream>>>(x, msk, adj, W1, b1, W2, b2,
                                           (float*)d_out);
}

// Round 11
// 116.044 us; speedup vs baseline: 1.1343x; 1.1343x over previous
//
#include <hip/hip_runtime.h>
#include <hip/hip_bf16.h>
#include <math.h>

#define NQ   9
#define NDIM 256
#define NHID 130
#define NST  512
#define NBATCH 64
#define P_TAYLOR 18
#define THETA 4.0f

__device__ __forceinline__ float softplusf(float x) {
    return (x > 0.f) ? (x + log1pf(expf(-x))) : log1pf(expf(x));
}

// ONE WAVE (64 threads) per batch element; 8 states per lane.
// State s = (lane << 3) | r  (s bits [8:3]=lane, [2:0]=reg index r).
// Qubit j lives at state-bit p = 8-j:
//   p in {3..8} -> cross-lane dir q = p-3 (shfl_xor, no barrier/LDS)
//   p in {0,1,2} -> in-lane register permutation (compile-time)
// Evolution: psi = e^{-i t c} * Prod_K [ Taylor_18( -i dt (H - c) ) ] e0,
// c = (maxD+minD)/2 (spectral shift), rho = (maxD-minD)/2 + (w/2)*sum(m),
// K = ceil(t*rho/4).  Barrier-free, LDS-free inner loop.
__global__ __launch_bounds__(64) void ryd_kernel(
    const float* __restrict__ x,    const float* __restrict__ mask,
    const float* __restrict__ adj,  const float* __restrict__ W1,
    const float* __restrict__ b1,   const float* __restrict__ W2,
    const float* __restrict__ b2,   float* __restrict__ out)
{
    const int b    = blockIdx.x;
    const int lane = threadIdx.x;   // 0..63, one wave

    __shared__ float xs[NDIM];
    __shared__ float hs[NHID];
    __shared__ float vs[4];
    __shared__ float ms[NQ];
    __shared__ float Wm[81];

    // ---- stage x, mask ----
    #pragma unroll
    for (int i = 0; i < 4; ++i) xs[lane + 64*i] = x[b*NDIM + lane + 64*i];
    if (lane < NQ) ms[lane] = mask[b*NQ + lane];
    __syncthreads();

    // ---- hidden = relu(x @ W1 + b1) ----
    for (int u = lane; u < NHID; u += 64) {
        float acc = b1[u];
        #pragma unroll 8
        for (int i = 0; i < NDIM; ++i) acc = fmaf(xs[i], W1[i*NHID + u], acc);
        hs[u] = fmaxf(acc, 0.f);
    }
    // ---- weighted adjacency ----
    for (int e = lane; e < 81; e += 64) {
        int i = e / 9, j = e % 9;
        Wm[e] = (866.0f/729.0f) * adj[e] * ms[i] * ms[j];
    }
    __syncthreads();

    // ---- v = hidden @ W2 + b2 ----
    if (lane < 4) {
        float acc = b2[lane];
        for (int j = 0; j < NHID; ++j) acc = fmaf(hs[j], W2[j*4 + lane], acc);
        vs[lane] = acc;
    }
    __syncthreads();

    // ---- pulse params (all lanes redundantly) ----
    const float omega = softplusf(vs[0]);
    const float delta = vs[1];
    const float phi   = vs[2];
    const float t     = softplusf(vs[3]);
    const float halfw = 0.5f * omega;
    const float Are   = halfw * cosf(phi);
    const float Aim   = halfw * sinf(phi);

    // ---- per-state diagonal (8 states per lane) ----
    float Dd[8];
    #pragma unroll
    for (int r = 0; r < 8; ++r) {
        const int s = (lane << 3) | r;
        float d = 0.f, mo = 0.f;
        #pragma unroll
        for (int i = 0; i < NQ; ++i) {
            float oi = ((s >> (8 - i)) & 1) ? 0.f : 1.f;
            mo = fmaf(ms[i], oi, mo);
            float row = 0.f;
            #pragma unroll
            for (int j = 0; j < NQ; ++j) {
                float oj = ((s >> (8 - j)) & 1) ? 0.f : 1.f;
                row = fmaf(Wm[i*9 + j], oj, row);
            }
            d = fmaf(oi, row, d);
        }
        Dd[r] = d - delta * mo;
    }

    // ---- exact diag range via wave reduction; shift + step count ----
    float mx = Dd[0], mn = Dd[0];
    #pragma unroll
    for (int r = 1; r < 8; ++r) { mx = fmaxf(mx, Dd[r]); mn = fminf(mn, Dd[r]); }
    #pragma unroll
    for (int off = 1; off < 64; off <<= 1) {
        mx = fmaxf(mx, __shfl_xor(mx, off));
        mn = fminf(mn, __shfl_xor(mn, off));
    }
    float sm = 0.f;
    #pragma unroll
    for (int j = 0; j < NQ; ++j) sm += ms[j];
    const float c   = 0.5f * (mx + mn);
    const float rho = 0.5f * (mx - mn) + halfw * sm;
    int K = (int)ceilf(t * rho / THETA);
    if (K < 1) K = 1;
    if (K > 200000) K = 200000;
    const float dt = t / (float)K;

    // ---- couplings ----
    // cross-lane dirs q=0..5 -> qubit j=5-q, bit=(lane>>q)&1
    float cxr[6], cxi[6];
    #pragma unroll
    for (int q = 0; q < 6; ++q) {
        const int j = 5 - q;
        const float sgn = ((lane >> q) & 1) ? -1.f : 1.f;
        cxr[q] = ms[j] * Are;
        cxi[q] = sgn * ms[j] * Aim;
    }
    // in-lane reg-bits p=0,1,2 -> qubit j=8-p; sign depends on (r>>p)&1 (compile-time)
    float inr[3], ini[3];
    #pragma unroll
    for (int p = 0; p < 3; ++p) { inr[p] = ms[8-p] * Are; ini[p] = ms[8-p] * Aim; }

    float DdC[8];
    #pragma unroll
    for (int r = 0; r < 8; ++r) DdC[r] = Dd[r] - c;

    // ---- evolve ----
    float cre[8], cim[8], ar_[8], ai_[8];
    #pragma unroll
    for (int r = 0; r < 8; ++r) { cre[r] = 0.f; cim[r] = 0.f; }
    cre[0] = (lane == 0) ? 1.f : 0.f;

    for (int step = 0; step < K; ++step) {
        #pragma unroll
        for (int r = 0; r < 8; ++r) { ar_[r] = cre[r]; ai_[r] = cim[r]; }

        for (int k = 1; k <= P_TAYLOR; ++k) {
            float yre[8], yim[8];
            #pragma unroll
            for (int r = 0; r < 8; ++r) {
                yre[r] = DdC[r] * cre[r];
                yim[r] = DdC[r] * cim[r];
            }
            // in-lane qubits (register permutation, signs fold at compile time)
            #pragma unroll
            for (int p = 0; p < 3; ++p) {
                #pragma unroll
                for (int r = 0; r < 8; ++r) {
                    const int rp = r ^ (1 << p);
                    const float bi = ((r >> p) & 1) ? -ini[p] : ini[p];
                    yre[r] += inr[p]*cre[rp] - bi*cim[rp];
                    yim[r] += inr[p]*cim[rp] + bi*cre[rp];
                }
            }
            // cross-lane qubits (shfl_xor)
            #pragma unroll
            for (int q = 0; q < 6; ++q) {
                #pragma unroll
                for (int r = 0; r < 8; ++r) {
                    const float zre = __shfl_xor(cre[r], 1 << q);
                    const float zim = __shfl_xor(cim[r], 1 << q);
                    yre[r] += cxr[q]*zre - cxi[q]*zim;
                    yim[r] += cxr[q]*zim + cxi[q]*zre;
                }
            }
            const float al = dt / (float)k;
            #pragma unroll
            for (int r = 0; r < 8; ++r) {
                const float nr =  al * yim[r];
                const float ni = -al * yre[r];
                cre[r] = nr; cim[r] = ni;
                ar_[r] += nr; ai_[r] += ni;
            }
        }
        #pragma unroll
        for (int r = 0; r < 8; ++r) { cre[r] = ar_[r]; cim[r] = ai_[r]; }
    }

    // ---- global phase e^{-i t c}; store real part ----
    const float th = t * c;
    float sth, cth;
    __sincosf(th, &sth, &cth);
    #pragma unroll
    for (int r = 0; r < 8; ++r)
        out[b*NST + (lane << 3) + r] = ar_[r]*cth + ai_[r]*sth;
}

extern "C" void kernel_launch(void* const* d_in, const int* in_sizes, int n_in,
                              void* d_out, int out_size, void* d_ws, size_t ws_size,
                              hipStream_t stream) {
    // Size-keyed input routing (pairwise-distinct element counts):
    //   x:16384  mask:576  adj:81  W1:33280  b1:130  W2:520  b2:4
    const float *x = nullptr, *msk = nullptr, *adj = nullptr,
                *W1 = nullptr, *b1 = nullptr, *W2 = nullptr, *b2 = nullptr;
    for (int i = 0; i < n_in; ++i) {
        const float* p = (const float*)d_in[i];
        switch (in_sizes[i]) {
            case 16384: x   = p; break;
            case 576:   msk = p; break;
            case 81:    adj = p; break;
            case 33280: W1  = p; break;
            case 130:   b1  = p; break;
            case 520:   W2  = p; break;
            case 4:     b2  = p; break;
            default: break;
        }
    }
    ryd_kernel<<<NBATCH, 64, 0, stream>>>(x, msk, adj, W1, b1, W2, b2,
                                          (float*)d_out);
}

// Round 12
// 70.232 us; speedup vs baseline: 1.8743x; 1.6523x over previous
//
#include <hip/hip_runtime.h>
#include <math.h>

#define NQ     9
#define NDIM   256
#define NHID   130
#define NST    512
#define NBATCH 64
#define MCAP   460

__device__ __forceinline__ float softplusf(float x) {
    return (x > 0.f) ? (x + log1pf(expf(-x))) : log1pf(expf(x));
}

// DPP-based XOR lane swaps (VALU pipe, no DS latency):
//   xor1 = quad_perm[1,0,3,2]=0xB1, xor2 = quad_perm[2,3,0,1]=0x4E,
//   xor7 = row_half_mirror=0x141, xor15 = row_mirror=0x140,
//   xor4 = xor3(0x1B) o xor7,  xor8 = xor15 o xor7.
template<int CTRL>
__device__ __forceinline__ float dpp_f(float v) {
    int i = __float_as_int(v);
    return __int_as_float(__builtin_amdgcn_update_dpp(i, i, CTRL, 0xF, 0xF, false));
}
__device__ __forceinline__ float swzx16(float v) {   // lane ^ 16 (within 32)
    return __int_as_float(__builtin_amdgcn_ds_swizzle(__float_as_int(v), 0x401F));
}
__device__ __forceinline__ float bperm(int addr, float v) {   // lane ^ 32
    return __int_as_float(__builtin_amdgcn_ds_bpermute(addr, __float_as_int(v)));
}

// y = (2*xhat)*cur;  NR = y - NR  (Chebyshev step, in place into prev)
#define MV(NR, NI, CR, CI)                                                    \
  do {                                                                        \
    _Pragma("unroll")                                                         \
    for (int r = 0; r < 8; ++r) {                                             \
      const float a = CR[r], bb = CI[r];                                      \
      float yr = dg2[r] * a, yi = dg2[r] * bb;                                \
      { const float s0 = (r & 1) ? -in2i[0] : in2i[0];                        \
        yr += in2r[0]*CR[r^1] - s0*CI[r^1];                                   \
        yi += in2r[0]*CI[r^1] + s0*CR[r^1]; }                                 \
      { const float s1 = (r & 2) ? -in2i[1] : in2i[1];                        \
        yr += in2r[1]*CR[r^2] - s1*CI[r^2];                                   \
        yi += in2r[1]*CI[r^2] + s1*CR[r^2]; }                                 \
      { const float s2 = (r & 4) ? -in2i[2] : in2i[2];                        \
        yr += in2r[2]*CR[r^4] - s2*CI[r^4];                                   \
        yi += in2r[2]*CI[r^4] + s2*CR[r^4]; }                                 \
      { const float za = dpp_f<0xB1>(a), zb = dpp_f<0xB1>(bb);                \
        yr += cx2r[0]*za - cx2i[0]*zb; yi += cx2r[0]*zb + cx2i[0]*za; }       \
      { const float za = dpp_f<0x4E>(a), zb = dpp_f<0x4E>(bb);                \
        yr += cx2r[1]*za - cx2i[1]*zb; yi += cx2r[1]*zb + cx2i[1]*za; }       \
      { const float a7 = dpp_f<0x141>(a), b7 = dpp_f<0x141>(bb);              \
        { const float za = dpp_f<0x1B>(a7), zb = dpp_f<0x1B>(b7);             \
          yr += cx2r[2]*za - cx2i[2]*zb; yi += cx2r[2]*zb + cx2i[2]*za; }     \
        { const float za = dpp_f<0x140>(a7), zb = dpp_f<0x140>(b7);           \
          yr += cx2r[3]*za - cx2i[3]*zb; yi += cx2r[3]*zb + cx2i[3]*za; } }   \
      { const float za = swzx16(a), zb = swzx16(bb);                          \
        yr += cx2r[4]*za - cx2i[4]*zb; yi += cx2r[4]*zb + cx2i[4]*za; }       \
      { const float za = bperm(bpaddr, a), zb = bperm(bpaddr, bb);            \
        yr += cx2r[5]*za - cx2i[5]*zb; yi += cx2r[5]*zb + cx2i[5]*za; }       \
      NR[r] = yr - NR[r];                                                     \
      NI[r] = yi - NI[r];                                                     \
    }                                                                         \
  } while (0)

#define COEF(PR, PI, K)                                                       \
  do { const float ck = 2.0f * jlf[K];                                        \
    switch ((K) & 3) {                                                        \
      case 0: _Pragma("unroll") for (int r=0;r<8;++r){accr[r]+=ck*PR[r];acci[r]+=ck*PI[r];} break; \
      case 1: _Pragma("unroll") for (int r=0;r<8;++r){accr[r]+=ck*PI[r];acci[r]-=ck*PR[r];} break; \
      case 2: _Pragma("unroll") for (int r=0;r<8;++r){accr[r]-=ck*PR[r];acci[r]-=ck*PI[r];} break; \
      case 3: _Pragma("unroll") for (int r=0;r<8;++r){accr[r]-=ck*PI[r];acci[r]+=ck*PR[r];} break; \
    }                                                                         \
  } while (0)

// ONE WAVE per batch element; 8 states/lane (s = lane<<3 | r).
// Chebyshev propagator: psi = e^{-itc} [ J0*v + sum_k 2(-i)^k J_k(z) T_k(xhat) v ],
// xhat=(H-c)/rho, z=t*rho. Cross-lane qubits via DPP (masks 1,2,4,8) +
// ds_swizzle (16) + ds_bpermute (32). Bessel table via Miller (double, lane 0).
__global__ __launch_bounds__(64) void ryd_kernel(
    const float* __restrict__ x,    const float* __restrict__ mask,
    const float* __restrict__ adj,  const float* __restrict__ W1,
    const float* __restrict__ b1,   const float* __restrict__ W2,
    const float* __restrict__ b2,   float* __restrict__ out)
{
    const int b    = blockIdx.x;
    const int lane = threadIdx.x;

    __shared__ float  xs[NDIM];
    __shared__ float  hs[NHID];
    __shared__ float  vs[4];
    __shared__ float  ms[NQ];
    __shared__ float  Wm[81];
    __shared__ double fd[MCAP + 4];
    __shared__ float  jlf[MCAP + 4];
    __shared__ double Ssh;

    // ---- stage x, mask ----
    #pragma unroll
    for (int i = 0; i < 4; ++i) xs[lane + 64*i] = x[b*NDIM + lane + 64*i];
    if (lane < NQ) ms[lane] = mask[b*NQ + lane];
    __syncthreads();

    // ---- hidden = relu(x @ W1 + b1) ----
    for (int u = lane; u < NHID; u += 64) {
        float acc = b1[u];
        #pragma unroll 8
        for (int i = 0; i < NDIM; ++i) acc = fmaf(xs[i], W1[i*NHID + u], acc);
        hs[u] = fmaxf(acc, 0.f);
    }
    for (int e = lane; e < 81; e += 64) {
        int i = e / 9, j = e % 9;
        Wm[e] = (866.0f/729.0f) * adj[e] * ms[i] * ms[j];
    }
    __syncthreads();

    // ---- v = hidden @ W2 + b2 ----
    if (lane < 4) {
        float acc = b2[lane];
        for (int j = 0; j < NHID; ++j) acc = fmaf(hs[j], W2[j*4 + lane], acc);
        vs[lane] = acc;
    }
    __syncthreads();

    const float omega = softplusf(vs[0]);
    const float delta = vs[1];
    const float phi   = vs[2];
    const float t     = softplusf(vs[3]);
    const float halfw = 0.5f * omega;
    const float Are   = halfw * cosf(phi);
    const float Aim   = halfw * sinf(phi);

    // ---- per-state diagonal ----
    float Dd[8];
    #pragma unroll
    for (int r = 0; r < 8; ++r) {
        const int s = (lane << 3) | r;
        float d = 0.f, mo = 0.f;
        #pragma unroll
        for (int i = 0; i < NQ; ++i) {
            float oi = ((s >> (8 - i)) & 1) ? 0.f : 1.f;
            mo = fmaf(ms[i], oi, mo);
            float row = 0.f;
            #pragma unroll
            for (int j = 0; j < NQ; ++j) {
                float oj = ((s >> (8 - j)) & 1) ? 0.f : 1.f;
                row = fmaf(Wm[i*9 + j], oj, row);
            }
            d = fmaf(oi, row, d);
        }
        Dd[r] = d - delta * mo;
    }

    // ---- spectral interval (exact diag range + Gershgorin off-diag) ----
    float mx = Dd[0], mn = Dd[0];
    #pragma unroll
    for (int r = 1; r < 8; ++r) { mx = fmaxf(mx, Dd[r]); mn = fminf(mn, Dd[r]); }
    #pragma unroll
    for (int off = 1; off < 64; off <<= 1) {
        mx = fmaxf(mx, __shfl_xor(mx, off));
        mn = fminf(mn, __shfl_xor(mn, off));
    }
    float sm = 0.f;
    #pragma unroll
    for (int j = 0; j < NQ; ++j) sm += ms[j];
    const float c0   = 0.5f * (mx + mn);
    float rho = (0.5f * (mx - mn) + halfw * sm) * 1.0155f;  // safety margin
    const float rhoE = fmaxf(rho, 1e-20f);
    const float zc   = t * rho;                              // >= 0

    // ---- term count ----
    int M;
    const bool tiny = (zc < 0.5f);
    if (tiny) M = 8;
    else {
        M = (int)ceilf(zc + 7.f * cbrtf(zc + 6.f) + 10.f);
        if (M > MCAP) M = MCAP;
    }

    // ---- Bessel table J_0..J_M ----
    if (tiny) {
        if (lane <= 8) {
            const float zh = 0.5f * zc;
            const float q  = zh * zh;
            float fact = 1.f;
            for (int i = 2; i <= lane; ++i) fact *= (float)i;
            const float pw = (lane == 0) ? 1.f : powf(zh, (float)lane);
            jlf[lane] = (pw / fact) *
                (1.f - q/(float)(lane+1) + 0.5f*q*q/(float)((lane+1)*(lane+2)));
        }
    } else {
        if (lane == 0) {
            const double zz  = (double)zc;
            const double inv = 1.0 / zz;
            const int   M2   = M + 20 + M/10;
            double fkp1 = 0.0, fk = 1e-30;
            for (int k = M2; k >= 1; --k) {
                double fkm1 = 2.0 * (double)k * inv * fk - fkp1;
                fkp1 = fk; fk = fkm1;
                const int idx = k - 1;
                if (idx <= M) fd[idx] = fk;
            }
            double S = fd[0];
            for (int idx = 2; idx <= M; idx += 2) S += 2.0 * fd[idx];
            Ssh = S;
        }
        __syncthreads();
        for (int k = lane; k <= M; k += 64) jlf[k] = (float)(fd[k] / Ssh);
    }
    __syncthreads();

    // ---- folded coefficients: 2*xhat ----
    const float two_rho = 2.0f / rhoE;
    float dg2[8];
    #pragma unroll
    for (int r = 0; r < 8; ++r) dg2[r] = (Dd[r] - c0) * two_rho;
    float cx2r[6], cx2i[6];
    #pragma unroll
    for (int q = 0; q < 6; ++q) {
        const float sgn = ((lane >> q) & 1) ? -1.f : 1.f;
        cx2r[q] = ms[5 - q] * Are * two_rho;
        cx2i[q] = sgn * ms[5 - q] * Aim * two_rho;
    }
    float in2r[3], in2i[3];
    #pragma unroll
    for (int p = 0; p < 3; ++p) {
        in2r[p] = ms[8 - p] * Are * two_rho;
        in2i[p] = ms[8 - p] * Aim * two_rho;
    }
    const int bpaddr = (lane ^ 32) << 2;

    // ---- Chebyshev recurrence ----
    float p0r[8], p0i[8], p1r[8], p1i[8], accr[8], acci[8];
    #pragma unroll
    for (int r = 0; r < 8; ++r) { p0r[r]=0.f; p0i[r]=0.f; p1r[r]=0.f; p1i[r]=0.f; }
    p0r[0] = (lane == 0) ? 1.f : 0.f;

    const float J0 = jlf[0];
    #pragma unroll
    for (int r = 0; r < 8; ++r) { accr[r] = J0 * p0r[r]; acci[r] = J0 * p0i[r]; }

    // phi1 = xhat * phi0  (MV gives 2*xhat*phi0 since p1 zeroed; halve)
    MV(p1r, p1i, p0r, p0i);
    #pragma unroll
    for (int r = 0; r < 8; ++r) { p1r[r] *= 0.5f; p1i[r] *= 0.5f; }
    { const float c1 = 2.0f * jlf[1];
      #pragma unroll
      for (int r = 0; r < 8; ++r) { accr[r] += c1*p1i[r]; acci[r] -= c1*p1r[r]; } }

    int k = 2;
    while (k <= M) {
        MV(p0r, p0i, p1r, p1i);   // p0 = 2*xhat*p1 - p0
        COEF(p0r, p0i, k);
        ++k;
        if (k > M) break;
        MV(p1r, p1i, p0r, p0i);   // p1 = 2*xhat*p0 - p1
        COEF(p1r, p1i, k);
        ++k;
    }

    // ---- global phase e^{-i t c0}; store real part ----
    const float th = t * c0;
    float sth, cth;
    __sincosf(th, &sth, &cth);
    #pragma unroll
    for (int r = 0; r < 8; ++r)
        out[b*NST + (lane << 3) + r] = accr[r]*cth + acci[r]*sth;
}

extern "C" void kernel_launch(void* const* d_in, const int* in_sizes, int n_in,
                              void* d_out, int out_size, void* d_ws, size_t ws_size,
                              hipStream_t stream) {
    // Size-keyed input routing (pairwise-distinct element counts):
    //   x:16384  mask:576  adj:81  W1:33280  b1:130  W2:520  b2:4
    const float *x = nullptr, *msk = nullptr, *adj = nullptr,
                *W1 = nullptr, *b1 = nullptr, *W2 = nullptr, *b2 = nullptr;
    for (int i = 0; i < n_in; ++i) {
        const float* p = (const float*)d_in[i];
        switch (in_sizes[i]) {
            case 16384: x   = p; break;
            case 576:   msk = p; break;
            case 81:    adj = p; break;
            case 33280: W1  = p; break;
            case 130:   b1  = p; break;
            case 520:   W2  = p; break;
            case 4:     b2  = p; break;
            default: break;
        }
    }
    ryd_kernel<<<NBATCH, 64, 0, stream>>>(x, msk, adj, W1, b1, W2, b2,
                                          (float*)d_out);
}

// Round 13
// 39.303 us; speedup vs baseline: 3.3491x; 1.7869x over previous
//
#include <hip/hip_runtime.h>
#include <math.h>

#define NQ     9
#define NDIM   256
#define NHID   130
#define NST    512
#define NBATCH 64
#define MCAP   460

__device__ __forceinline__ float softplusf(float x) {
    return (x > 0.f) ? (x + log1pf(expf(-x))) : log1pf(expf(x));
}

// DPP-based XOR lane swaps (VALU pipe):
//   xor1=quad_perm[1,0,3,2]=0xB1, xor2=quad_perm[2,3,0,1]=0x4E,
//   xor7=row_half_mirror=0x141, xor15=row_mirror=0x140,
//   xor4=0x1B(xor3) o xor7, xor8=0x140(xor15) o xor7.
template<int CTRL>
__device__ __forceinline__ float dpp_f(float v) {
    int i = __float_as_int(v);
    return __int_as_float(__builtin_amdgcn_update_dpp(i, i, CTRL, 0xF, 0xF, false));
}
__device__ __forceinline__ float swzx16(float v) {   // lane ^ 16
    return __int_as_float(__builtin_amdgcn_ds_swizzle(__float_as_int(v), 0x401F));
}
__device__ __forceinline__ float bperm(int addr, float v) {   // lane ^ 32
    return __int_as_float(__builtin_amdgcn_ds_bpermute(addr, __float_as_int(v)));
}

// Chebyshev step on REAL vectors: NR = (2*xhat)*CR - NR
#define MV(NR, CR)                                                            \
  do {                                                                        \
    float z16[8], z32[8];                                                     \
    _Pragma("unroll")                                                         \
    for (int r = 0; r < 8; ++r) {                                             \
      z16[r] = swzx16(CR[r]);                                                 \
      z32[r] = bperm(bpaddr, CR[r]);                                          \
    }                                                                         \
    _Pragma("unroll")                                                         \
    for (int r = 0; r < 8; ++r) {                                             \
      float yr = dg2[r] * CR[r];                                              \
      yr = fmaf(in2[0], CR[r^1], yr);                                         \
      yr = fmaf(in2[1], CR[r^2], yr);                                         \
      yr = fmaf(in2[2], CR[r^4], yr);                                         \
      yr = fmaf(cx2[0], dpp_f<0xB1>(CR[r]), yr);                              \
      yr = fmaf(cx2[1], dpp_f<0x4E>(CR[r]), yr);                              \
      const float a7 = dpp_f<0x141>(CR[r]);                                   \
      yr = fmaf(cx2[2], dpp_f<0x1B>(a7), yr);                                 \
      yr = fmaf(cx2[3], dpp_f<0x140>(a7), yr);                                \
      yr = fmaf(cx2[4], z16[r], yr);                                          \
      yr = fmaf(cx2[5], z32[r], yr);                                          \
      NR[r] = yr - NR[r];                                                     \
    }                                                                         \
  } while (0)

// accumulate 2*(-i)^k*J_k * p  (p real):
//   k%4==0: accr += ; 1: acci -= ; 2: accr -= ; 3: acci +=
#define COEF(P, K)                                                            \
  do { const float ck = 2.0f * jlf[K];                                        \
    switch ((K) & 3) {                                                        \
      case 0: _Pragma("unroll") for (int r=0;r<8;++r) accr[r] += ck*P[r]; break; \
      case 1: _Pragma("unroll") for (int r=0;r<8;++r) acci[r] -= ck*P[r]; break; \
      case 2: _Pragma("unroll") for (int r=0;r<8;++r) accr[r] -= ck*P[r]; break; \
      case 3: _Pragma("unroll") for (int r=0;r<8;++r) acci[r] += ck*P[r]; break; \
    }                                                                         \
  } while (0)

// ONE WAVE per batch element; 8 states/lane (s = lane<<3 | r).
// GAUGE TRANSFORM: U = diag(e^{i phi n1(s)}) makes H' = U H U^dag REAL
// symmetric (off-diag m_j*w/2, diag unchanged); U e0 = e0. Chebyshev vectors
// T_k(xhat')e0 are REAL; complex enters only via (-i)^k J_k(z) coefficients
// and the final per-state phase e^{-i(t c0 + phi n1(s))}.
__global__ __launch_bounds__(64) void ryd_kernel(
    const float* __restrict__ x,    const float* __restrict__ mask,
    const float* __restrict__ adj,  const float* __restrict__ W1,
    const float* __restrict__ b1,   const float* __restrict__ W2,
    const float* __restrict__ b2,   float* __restrict__ out)
{
    const int b    = blockIdx.x;
    const int lane = threadIdx.x;

    __shared__ float  xs[NDIM];
    __shared__ float  hs[NHID];
    __shared__ float  vs[4];
    __shared__ float  ms[NQ];
    __shared__ float  Wm[81];
    __shared__ double fd[MCAP + 4];
    __shared__ float  jlf[MCAP + 4];
    __shared__ double Ssh;

    // ---- stage x, mask ----
    #pragma unroll
    for (int i = 0; i < 4; ++i) xs[lane + 64*i] = x[b*NDIM + lane + 64*i];
    if (lane < NQ) ms[lane] = mask[b*NQ + lane];
    __syncthreads();

    // ---- hidden = relu(x @ W1 + b1) ----
    for (int u = lane; u < NHID; u += 64) {
        float acc = b1[u];
        #pragma unroll 8
        for (int i = 0; i < NDIM; ++i) acc = fmaf(xs[i], W1[i*NHID + u], acc);
        hs[u] = fmaxf(acc, 0.f);
    }
    for (int e = lane; e < 81; e += 64) {
        int i = e / 9, j = e % 9;
        Wm[e] = (866.0f/729.0f) * adj[e] * ms[i] * ms[j];
    }
    __syncthreads();

    // ---- v = hidden @ W2 + b2 ----
    if (lane < 4) {
        float acc = b2[lane];
        for (int j = 0; j < NHID; ++j) acc = fmaf(hs[j], W2[j*4 + lane], acc);
        vs[lane] = acc;
    }
    __syncthreads();

    const float omega = softplusf(vs[0]);
    const float delta = vs[1];
    const float phi   = vs[2];
    const float t     = softplusf(vs[3]);
    const float halfw = 0.5f * omega;

    // ---- per-state diagonal ----
    float Dd[8];
    #pragma unroll
    for (int r = 0; r < 8; ++r) {
        const int s = (lane << 3) | r;
        float d = 0.f, mo = 0.f;
        #pragma unroll
        for (int i = 0; i < NQ; ++i) {
            float oi = ((s >> (8 - i)) & 1) ? 0.f : 1.f;
            mo = fmaf(ms[i], oi, mo);
            float row = 0.f;
            #pragma unroll
            for (int j = 0; j < NQ; ++j) {
                float oj = ((s >> (8 - j)) & 1) ? 0.f : 1.f;
                row = fmaf(Wm[i*9 + j], oj, row);
            }
            d = fmaf(oi, row, d);
        }
        Dd[r] = d - delta * mo;
    }

    // ---- spectral interval; shift + scale ----
    float mx = Dd[0], mn = Dd[0];
    #pragma unroll
    for (int r = 1; r < 8; ++r) { mx = fmaxf(mx, Dd[r]); mn = fminf(mn, Dd[r]); }
    #pragma unroll
    for (int off = 1; off < 64; off <<= 1) {
        mx = fmaxf(mx, __shfl_xor(mx, off));
        mn = fminf(mn, __shfl_xor(mn, off));
    }
    float sm = 0.f;
    #pragma unroll
    for (int j = 0; j < NQ; ++j) sm += ms[j];
    const float c0   = 0.5f * (mx + mn);
    const float rho  = (0.5f * (mx - mn) + halfw * sm) * 1.0155f;
    const float rhoE = fmaxf(rho, 1e-20f);
    const float zc   = t * rho;

    // ---- term count ----
    int M;
    const bool tiny = (zc < 0.5f);
    if (tiny) M = 8;
    else {
        M = (int)ceilf(zc + 6.f * cbrtf(zc + 6.f) + 8.f);
        if (M > MCAP) M = MCAP;
    }

    // ---- Bessel table J_0..J_M ----
    if (tiny) {
        if (lane <= 8) {
            const float zh = 0.5f * zc;
            const float q  = zh * zh;
            float fact = 1.f;
            for (int i = 2; i <= lane; ++i) fact *= (float)i;
            const float pw = (lane == 0) ? 1.f : powf(zh, (float)lane);
            jlf[lane] = (pw / fact) *
                (1.f - q/(float)(lane+1) + 0.5f*q*q/(float)((lane+1)*(lane+2)));
        }
    } else {
        if (lane == 0) {
            const double zz  = (double)zc;
            const double inv = 1.0 / zz;
            const int   M2   = M + 20 + M/10;
            double fkp1 = 0.0, fk = 1e-30;
            for (int k = M2; k >= 1; --k) {
                double fkm1 = 2.0 * (double)k * inv * fk - fkp1;
                fkp1 = fk; fk = fkm1;
                const int idx = k - 1;
                if (idx <= M) fd[idx] = fk;
            }
            double S = fd[0];
            for (int idx = 2; idx <= M; idx += 2) S += 2.0 * fd[idx];
            Ssh = S;
        }
        __syncthreads();
        for (int k = lane; k <= M; k += 64) jlf[k] = (float)(fd[k] / Ssh);
    }
    __syncthreads();

    // ---- folded REAL coefficients of 2*xhat ----
    const float two_rho = 2.0f / rhoE;
    float dg2[8];
    #pragma unroll
    for (int r = 0; r < 8; ++r) dg2[r] = (Dd[r] - c0) * two_rho;
    float cx2[6];
    #pragma unroll
    for (int q = 0; q < 6; ++q) cx2[q] = ms[5 - q] * halfw * two_rho;
    float in2[3];
    #pragma unroll
    for (int p = 0; p < 3; ++p) in2[p] = ms[8 - p] * halfw * two_rho;
    const int bpaddr = (lane ^ 32) << 2;

    // ---- Chebyshev recurrence (REAL vectors) ----
    float p0[8], p1[8], accr[8], acci[8];
    #pragma unroll
    for (int r = 0; r < 8; ++r) { p0[r] = 0.f; p1[r] = 0.f; acci[r] = 0.f; }
    p0[0] = (lane == 0) ? 1.f : 0.f;

    const float J0 = jlf[0];
    #pragma unroll
    for (int r = 0; r < 8; ++r) accr[r] = J0 * p0[r];

    // p1 = xhat * p0  (MV into zeroed p1 gives 2*xhat*p0; halve)
    MV(p1, p0);
    #pragma unroll
    for (int r = 0; r < 8; ++r) p1[r] *= 0.5f;
    { const float c1 = 2.0f * jlf[1];
      #pragma unroll
      for (int r = 0; r < 8; ++r) acci[r] -= c1 * p1[r]; }

    int k = 2;
    while (k <= M) {
        MV(p0, p1);   // p0 = 2*xhat*p1 - p0
        COEF(p0, k);
        ++k;
        if (k > M) break;
        MV(p1, p0);   // p1 = 2*xhat*p0 - p1
        COEF(p1, k);
        ++k;
    }

    // ---- undo gauge + shift: psi_s = e^{-i(t c0 + phi n1(s))} chi_s ----
    const float base = t * c0;
    const float pcl  = (float)__popc(lane);
    #pragma unroll
    for (int r = 0; r < 8; ++r) {
        const float beta = base + phi * (pcl + (float)__popc(r));
        float sb, cbta;
        __sincosf(beta, &sb, &cbta);
        out[b*NST + (lane << 3) + r] = accr[r]*cbta + acci[r]*sb;
    }
}

extern "C" void kernel_launch(void* const* d_in, const int* in_sizes, int n_in,
                              void* d_out, int out_size, void* d_ws, size_t ws_size,
                              hipStream_t stream) {
    // Size-keyed input routing (pairwise-distinct element counts):
    //   x:16384  mask:576  adj:81  W1:33280  b1:130  W2:520  b2:4
    const float *x = nullptr, *msk = nullptr, *adj = nullptr,
                *W1 = nullptr, *b1 = nullptr, *W2 = nullptr, *b2 = nullptr;
    for (int i = 0; i < n_in; ++i) {
        const float* p = (const float*)d_in[i];
        switch (in_sizes[i]) {
            case 16384: x   = p; break;
            case 576:   msk = p; break;
            case 81:    adj = p; break;
            case 33280: W1  = p; break;
            case 130:   b1  = p; break;
            case 520:   W2  = p; break;
            case 4:     b2  = p; break;
            default: break;
        }
    }
    ryd_kernel<<<NBATCH, 64, 0, stream>>>(x, msk, adj, W1, b1, W2, b2,
                                          (float*)d_out);
}

// Round 14
// 30.386 us; speedup vs baseline: 4.3320x; 1.2935x over previous
//
#include <hip/hip_runtime.h>
#include <math.h>

#define NQ     9
#define NDIM   256
#define NHID   130
#define NST    512
#define NBATCH 64
#define MCAP   460

__device__ __forceinline__ float softplusf(float x) {
    return (x > 0.f) ? (x + log1pf(expf(-x))) : log1pf(expf(x));
}

// ---------------- Kernel A: MLP for all 64 batches -> ws[b*4+w] -------------
// 64 blocks x 256 threads (4 waves/CU): 4x the outstanding loads on the W1
// stream vs R13's single wave; 64 CUs co-stream W1 so L2 warms fast.
__global__ __launch_bounds__(256) void mlp_kernel(
    const float* __restrict__ x,  const float* __restrict__ W1,
    const float* __restrict__ b1, const float* __restrict__ W2,
    const float* __restrict__ b2, float* __restrict__ vout)
{
    const int b = blockIdx.x, tid = threadIdx.x;
    __shared__ float xs[NDIM];
    __shared__ float hs[NHID + 2];
    xs[tid] = x[b*NDIM + tid];
    __syncthreads();
    if (tid < NHID) {
        float acc = b1[tid];
        #pragma unroll 16
        for (int i = 0; i < NDIM; ++i) acc = fmaf(xs[i], W1[i*NHID + tid], acc);
        hs[tid] = fmaxf(acc, 0.f);
    }
    __syncthreads();
    // layer 2: warp w (0..3) computes v[w] by wave-reduction over hidden units
    const int w = tid >> 6, lane = tid & 63;
    float p = hs[lane]      * W2[lane*4 + w]
            + hs[lane + 64] * W2[(lane + 64)*4 + w];
    if (lane < 2) p += hs[128 + lane] * W2[(128 + lane)*4 + w];
    #pragma unroll
    for (int off = 32; off; off >>= 1) p += __shfl_down(p, off);
    if (lane == 0) vout[b*4 + w] = p + b2[w];
}

// ---------------- Kernel B: Chebyshev evolution (unchanged math) ------------
// DPP-based XOR lane swaps (VALU pipe):
template<int CTRL>
__device__ __forceinline__ float dpp_f(float v) {
    int i = __float_as_int(v);
    return __int_as_float(__builtin_amdgcn_update_dpp(i, i, CTRL, 0xF, 0xF, false));
}
__device__ __forceinline__ float swzx16(float v) {   // lane ^ 16
    return __int_as_float(__builtin_amdgcn_ds_swizzle(__float_as_int(v), 0x401F));
}
__device__ __forceinline__ float bperm(int addr, float v) {   // lane ^ 32
    return __int_as_float(__builtin_amdgcn_ds_bpermute(addr, __float_as_int(v)));
}

// Chebyshev step on REAL vectors: NR = (2*xhat)*CR - NR
#define MV(NR, CR)                                                            \
  do {                                                                        \
    float z16[8], z32[8];                                                     \
    _Pragma("unroll")                                                         \
    for (int r = 0; r < 8; ++r) {                                             \
      z16[r] = swzx16(CR[r]);                                                 \
      z32[r] = bperm(bpaddr, CR[r]);                                          \
    }                                                                         \
    _Pragma("unroll")                                                         \
    for (int r = 0; r < 8; ++r) {                                             \
      float yr = dg2[r] * CR[r];                                              \
      yr = fmaf(in2[0], CR[r^1], yr);                                         \
      yr = fmaf(in2[1], CR[r^2], yr);                                         \
      yr = fmaf(in2[2], CR[r^4], yr);                                         \
      yr = fmaf(cx2[0], dpp_f<0xB1>(CR[r]), yr);                              \
      yr = fmaf(cx2[1], dpp_f<0x4E>(CR[r]), yr);                              \
      const float a7 = dpp_f<0x141>(CR[r]);                                   \
      yr = fmaf(cx2[2], dpp_f<0x1B>(a7), yr);                                 \
      yr = fmaf(cx2[3], dpp_f<0x140>(a7), yr);                                \
      yr = fmaf(cx2[4], z16[r], yr);                                          \
      yr = fmaf(cx2[5], z32[r], yr);                                          \
      NR[r] = yr - NR[r];                                                     \
    }                                                                         \
  } while (0)

#define COEF(P, K)                                                            \
  do { const float ck = 2.0f * jlf[K];                                        \
    switch ((K) & 3) {                                                        \
      case 0: _Pragma("unroll") for (int r=0;r<8;++r) accr[r] += ck*P[r]; break; \
      case 1: _Pragma("unroll") for (int r=0;r<8;++r) acci[r] -= ck*P[r]; break; \
      case 2: _Pragma("unroll") for (int r=0;r<8;++r) accr[r] -= ck*P[r]; break; \
      case 3: _Pragma("unroll") for (int r=0;r<8;++r) acci[r] += ck*P[r]; break; \
    }                                                                         \
  } while (0)

// ONE WAVE per batch element; 8 states/lane (s = lane<<3 | r).
// Gauge transform makes H' real; Chebyshev vectors real; complex only in
// (-i)^k J_k coefficients and final per-state phase.
__global__ __launch_bounds__(64) void ryd_kernel(
    const float* __restrict__ vin,  const float* __restrict__ mask,
    const float* __restrict__ adj,  float* __restrict__ out)
{
    const int b    = blockIdx.x;
    const int lane = threadIdx.x;

    __shared__ float  ms[NQ];
    __shared__ float  Wm[81];
    __shared__ double fd[MCAP + 4];
    __shared__ float  jlf[MCAP + 4];
    __shared__ double Ssh;

    if (lane < NQ) ms[lane] = mask[b*NQ + lane];
    __syncthreads();
    for (int e = lane; e < 81; e += 64) {
        int i = e / 9, j = e % 9;
        Wm[e] = (866.0f/729.0f) * adj[e] * ms[i] * ms[j];
    }
    __syncthreads();

    const float omega = softplusf(vin[b*4 + 0]);
    const float delta = vin[b*4 + 1];
    const float phi   = vin[b*4 + 2];
    const float t     = softplusf(vin[b*4 + 3]);
    const float halfw = 0.5f * omega;

    // ---- per-state diagonal ----
    float Dd[8];
    #pragma unroll
    for (int r = 0; r < 8; ++r) {
        const int s = (lane << 3) | r;
        float d = 0.f, mo = 0.f;
        #pragma unroll
        for (int i = 0; i < NQ; ++i) {
            float oi = ((s >> (8 - i)) & 1) ? 0.f : 1.f;
            mo = fmaf(ms[i], oi, mo);
            float row = 0.f;
            #pragma unroll
            for (int j = 0; j < NQ; ++j) {
                float oj = ((s >> (8 - j)) & 1) ? 0.f : 1.f;
                row = fmaf(Wm[i*9 + j], oj, row);
            }
            d = fmaf(oi, row, d);
        }
        Dd[r] = d - delta * mo;
    }

    // ---- spectral interval ----
    float mx = Dd[0], mn = Dd[0];
    #pragma unroll
    for (int r = 1; r < 8; ++r) { mx = fmaxf(mx, Dd[r]); mn = fminf(mn, Dd[r]); }
    #pragma unroll
    for (int off = 1; off < 64; off <<= 1) {
        mx = fmaxf(mx, __shfl_xor(mx, off));
        mn = fminf(mn, __shfl_xor(mn, off));
    }
    float sm = 0.f;
    #pragma unroll
    for (int j = 0; j < NQ; ++j) sm += ms[j];
    const float c0   = 0.5f * (mx + mn);
    const float rho  = (0.5f * (mx - mn) + halfw * sm) * 1.0155f;
    const float rhoE = fmaxf(rho, 1e-20f);
    const float zc   = t * rho;

    int M;
    const bool tiny = (zc < 0.5f);
    if (tiny) M = 8;
    else {
        M = (int)ceilf(zc + 6.f * cbrtf(zc + 6.f) + 8.f);
        if (M > MCAP) M = MCAP;
    }

    // ---- Bessel table J_0..J_M ----
    if (tiny) {
        if (lane <= 8) {
            const float zh = 0.5f * zc;
            const float q  = zh * zh;
            float fact = 1.f;
            for (int i = 2; i <= lane; ++i) fact *= (float)i;
            const float pw = (lane == 0) ? 1.f : powf(zh, (float)lane);
            jlf[lane] = (pw / fact) *
                (1.f - q/(float)(lane+1) + 0.5f*q*q/(float)((lane+1)*(lane+2)));
        }
    } else {
        if (lane == 0) {
            const double zz  = (double)zc;
            const double inv = 1.0 / zz;
            const int   M2   = M + 20 + M/10;
            double fkp1 = 0.0, fk = 1e-30;
            for (int k = M2; k >= 1; --k) {
                double fkm1 = 2.0 * (double)k * inv * fk - fkp1;
                fkp1 = fk; fk = fkm1;
                const int idx = k - 1;
                if (idx <= M) fd[idx] = fk;
            }
            double S = fd[0];
            for (int idx = 2; idx <= M; idx += 2) S += 2.0 * fd[idx];
            Ssh = S;
        }
        __syncthreads();
        for (int k = lane; k <= M; k += 64) jlf[k] = (float)(fd[k] / Ssh);
    }
    __syncthreads();

    // ---- folded REAL coefficients of 2*xhat ----
    const float two_rho = 2.0f / rhoE;
    float dg2[8];
    #pragma unroll
    for (int r = 0; r < 8; ++r) dg2[r] = (Dd[r] - c0) * two_rho;
    float cx2[6];
    #pragma unroll
    for (int q = 0; q < 6; ++q) cx2[q] = ms[5 - q] * halfw * two_rho;
    float in2[3];
    #pragma unroll
    for (int p = 0; p < 3; ++p) in2[p] = ms[8 - p] * halfw * two_rho;
    const int bpaddr = (lane ^ 32) << 2;

    // ---- Chebyshev recurrence (REAL vectors) ----
    float p0[8], p1[8], accr[8], acci[8];
    #pragma unroll
    for (int r = 0; r < 8; ++r) { p0[r] = 0.f; p1[r] = 0.f; acci[r] = 0.f; }
    p0[0] = (lane == 0) ? 1.f : 0.f;

    const float J0 = jlf[0];
    #pragma unroll
    for (int r = 0; r < 8; ++r) accr[r] = J0 * p0[r];

    MV(p1, p0);
    #pragma unroll
    for (int r = 0; r < 8; ++r) p1[r] *= 0.5f;
    { const float c1 = 2.0f * jlf[1];
      #pragma unroll
      for (int r = 0; r < 8; ++r) acci[r] -= c1 * p1[r]; }

    int k = 2;
    while (k <= M) {
        MV(p0, p1);
        COEF(p0, k);
        ++k;
        if (k > M) break;
        MV(p1, p0);
        COEF(p1, k);
        ++k;
    }

    // ---- undo gauge + shift ----
    const float base = t * c0;
    const float pcl  = (float)__popc(lane);
    #pragma unroll
    for (int r = 0; r < 8; ++r) {
        const float beta = base + phi * (pcl + (float)__popc(r));
        float sb, cbta;
        __sincosf(beta, &sb, &cbta);
        out[b*NST + (lane << 3) + r] = accr[r]*cbta + acci[r]*sb;
    }
}

extern "C" void kernel_launch(void* const* d_in, const int* in_sizes, int n_in,
                              void* d_out, int out_size, void* d_ws, size_t ws_size,
                              hipStream_t stream) {
    // Size-keyed input routing (pairwise-distinct element counts):
    //   x:16384  mask:576  adj:81  W1:33280  b1:130  W2:520  b2:4
    const float *x = nullptr, *msk = nullptr, *adj = nullptr,
                *W1 = nullptr, *b1 = nullptr, *W2 = nullptr, *b2 = nullptr;
    for (int i = 0; i < n_in; ++i) {
        const float* p = (const float*)d_in[i];
        switch (in_sizes[i]) {
            case 16384: x   = p; break;
            case 576:   msk = p; break;
            case 81:    adj = p; break;
            case 33280: W1  = p; break;
            case 130:   b1  = p; break;
            case 520:   W2  = p; break;
            case 4:     b2  = p; break;
            default: break;
        }
    }
    float* v = (float*)d_ws;   // 64*4 floats, written by A before B reads
    mlp_kernel<<<NBATCH, 256, 0, stream>>>(x, W1, b1, W2, b2, v);
    ryd_kernel<<<NBATCH, 64, 0, stream>>>(v, msk, adj, (float*)d_out);
}

// Round 15
// 27.116 us; speedup vs baseline: 4.8544x; 1.1206x over previous
//
#include <hip/hip_runtime.h>
#include <math.h>

#define NQ     9
#define NDIM   256
#define NHID   130
#define NST    512
#define NBATCH 64
#define MCAP   460

__device__ __forceinline__ float softplusf(float x) {
    return (x > 0.f) ? (x + log1pf(expf(-x))) : log1pf(expf(x));
}

// DPP-based XOR lane swaps (VALU pipe):
template<int CTRL>
__device__ __forceinline__ float dpp_f(float v) {
    int i = __float_as_int(v);
    return __int_as_float(__builtin_amdgcn_update_dpp(i, i, CTRL, 0xF, 0xF, false));
}
__device__ __forceinline__ float swzx16(float v) {   // lane ^ 16
    return __int_as_float(__builtin_amdgcn_ds_swizzle(__float_as_int(v), 0x401F));
}
__device__ __forceinline__ float bperm(int addr, float v) {   // lane ^ 32
    return __int_as_float(__builtin_amdgcn_ds_bpermute(addr, __float_as_int(v)));
}

// Chebyshev step on REAL vectors: NR = (2*xhat)*CR - NR
#define MV(NR, CR)                                                            \
  do {                                                                        \
    float z16[8], z32[8];                                                     \
    _Pragma("unroll")                                                         \
    for (int r = 0; r < 8; ++r) {                                             \
      z16[r] = swzx16(CR[r]);                                                 \
      z32[r] = bperm(bpaddr, CR[r]);                                          \
    }                                                                         \
    _Pragma("unroll")                                                         \
    for (int r = 0; r < 8; ++r) {                                             \
      float yr = dg2[r] * CR[r];                                              \
      yr = fmaf(in2[0], CR[r^1], yr);                                         \
      yr = fmaf(in2[1], CR[r^2], yr);                                         \
      yr = fmaf(in2[2], CR[r^4], yr);                                         \
      yr = fmaf(cx2[0], dpp_f<0xB1>(CR[r]), yr);                              \
      yr = fmaf(cx2[1], dpp_f<0x4E>(CR[r]), yr);                              \
      const float a7 = dpp_f<0x141>(CR[r]);                                   \
      yr = fmaf(cx2[2], dpp_f<0x1B>(a7), yr);                                 \
      yr = fmaf(cx2[3], dpp_f<0x140>(a7), yr);                                \
      yr = fmaf(cx2[4], z16[r], yr);                                          \
      yr = fmaf(cx2[5], z32[r], yr);                                          \
      NR[r] = yr - NR[r];                                                     \
    }                                                                         \
  } while (0)

#define COEF(P, K)                                                            \
  do { const float ck = 2.0f * jlf[K];                                        \
    switch ((K) & 3) {                                                        \
      case 0: _Pragma("unroll") for (int r=0;r<8;++r) accr[r] += ck*P[r]; break; \
      case 1: _Pragma("unroll") for (int r=0;r<8;++r) acci[r] -= ck*P[r]; break; \
      case 2: _Pragma("unroll") for (int r=0;r<8;++r) accr[r] -= ck*P[r]; break; \
      case 3: _Pragma("unroll") for (int r=0;r<8;++r) acci[r] += ck*P[r]; break; \
    }                                                                         \
  } while (0)

// FUSED: one block per batch, 256 threads.
// Phase 1 (4 waves): stage W1 -> LDS coalesced; MLP layer1 from LDS; layer2
//   per-warp reduction -> vs[].
// Phase 2 (wave 0 only, waves 1-3 exit): gauge-transformed REAL Chebyshev
//   evolution, barrier-free (single-wave lockstep); Bessel tables alias the
//   dead W1 LDS region.
__global__ __launch_bounds__(256) void fused_kernel(
    const float* __restrict__ x,    const float* __restrict__ mask,
    const float* __restrict__ adj,  const float* __restrict__ W1,
    const float* __restrict__ b1,   const float* __restrict__ W2,
    const float* __restrict__ b2,   float* __restrict__ out)
{
    const int b   = blockIdx.x;
    const int tid = threadIdx.x;

    __shared__ __align__(16) float w1s[NDIM * NHID];   // 133 KB; reused later
    __shared__ float xs[NDIM];
    __shared__ float hs[NHID + 2];
    __shared__ float vs[4];
    __shared__ float ms[NQ];
    __shared__ float Wm[81];
    __shared__ double Ssh;

    // ---- stage W1 (coalesced float4), x, mask ----
    {
        const float4* W14 = (const float4*)W1;
        float4* d4 = (float4*)w1s;
        #pragma unroll 4
        for (int i = tid; i < (NDIM*NHID)/4; i += 256) d4[i] = W14[i];
        if (tid < NDIM/4) ((float4*)xs)[tid] = ((const float4*)(x + b*NDIM))[tid];
        if (tid < NQ) ms[tid] = mask[b*NQ + tid];
    }
    __syncthreads();

    // ---- layer 1: hidden = relu(x @ W1 + b1), W1 from LDS ----
    if (tid < NHID) {
        float acc = b1[tid];
        #pragma unroll 8
        for (int i = 0; i < NDIM; ++i) acc = fmaf(xs[i], w1s[i*NHID + tid], acc);
        hs[tid] = fmaxf(acc, 0.f);
    }
    __syncthreads();

    // ---- layer 2: warp w computes v[w] via wave reduction ----
    const int w    = tid >> 6;
    const int lane = tid & 63;
    {
        float p = hs[lane]      * W2[lane*4 + w]
                + hs[lane + 64] * W2[(lane + 64)*4 + w];
        if (lane < 2) p += hs[128 + lane] * W2[(128 + lane)*4 + w];
        #pragma unroll
        for (int off = 32; off; off >>= 1) p += __shfl_down(p, off);
        if (lane == 0) vs[w] = p + b2[w];
    }
    __syncthreads();

    if (w != 0) return;   // waves 1-3 done; wave 0 evolves (lockstep, no barriers)

    // Bessel tables alias the dead W1 staging region.
    double* fd  = (double*)w1s;                  // (MCAP+4) doubles
    float*  jlf = w1s + 2*(MCAP + 8);            // after fd, 16B padded

    // ---- weighted adjacency (wave 0, lockstep) ----
    for (int e = lane; e < 81; e += 64) {
        int i = e / 9, j = e % 9;
        Wm[e] = (866.0f/729.0f) * adj[e] * ms[i] * ms[j];
    }

    const float omega = softplusf(vs[0]);
    const float delta = vs[1];
    const float phi   = vs[2];
    const float t     = softplusf(vs[3]);
    const float halfw = 0.5f * omega;

    // ---- per-state diagonal (8 states/lane; s = lane<<3 | r) ----
    float Dd[8];
    #pragma unroll
    for (int r = 0; r < 8; ++r) {
        const int s = (lane << 3) | r;
        float d = 0.f, mo = 0.f;
        #pragma unroll
        for (int i = 0; i < NQ; ++i) {
            float oi = ((s >> (8 - i)) & 1) ? 0.f : 1.f;
            mo = fmaf(ms[i], oi, mo);
            float row = 0.f;
            #pragma unroll
            for (int j = 0; j < NQ; ++j) {
                float oj = ((s >> (8 - j)) & 1) ? 0.f : 1.f;
                row = fmaf(Wm[i*9 + j], oj, row);
            }
            d = fmaf(oi, row, d);
        }
        Dd[r] = d - delta * mo;
    }

    // ---- spectral interval ----
    float mx = Dd[0], mn = Dd[0];
    #pragma unroll
    for (int r = 1; r < 8; ++r) { mx = fmaxf(mx, Dd[r]); mn = fminf(mn, Dd[r]); }
    #pragma unroll
    for (int off = 1; off < 64; off <<= 1) {
        mx = fmaxf(mx, __shfl_xor(mx, off));
        mn = fminf(mn, __shfl_xor(mn, off));
    }
    float sm = 0.f;
    #pragma unroll
    for (int j = 0; j < NQ; ++j) sm += ms[j];
    const float c0   = 0.5f * (mx + mn);
    const float rho  = (0.5f * (mx - mn) + halfw * sm) * 1.0155f;
    const float rhoE = fmaxf(rho, 1e-20f);
    const float zc   = t * rho;

    int M;
    const bool tiny = (zc < 0.5f);
    if (tiny) M = 8;
    else {
        M = (int)ceilf(zc + 4.5f * cbrtf(zc + 6.f) + 5.f);
        if (M > MCAP) M = MCAP;
    }

    // ---- Bessel table J_0..J_M (single-wave lockstep: no barriers) ----
    if (tiny) {
        if (lane <= 8) {
            const float zh = 0.5f * zc;
            const float q  = zh * zh;
            float fact = 1.f;
            for (int i = 2; i <= lane; ++i) fact *= (float)i;
            const float pw = (lane == 0) ? 1.f : powf(zh, (float)lane);
            jlf[lane] = (pw / fact) *
                (1.f - q/(float)(lane+1) + 0.5f*q*q/(float)((lane+1)*(lane+2)));
        }
    } else {
        if (lane == 0) {
            const double zz  = (double)zc;
            const double inv = 1.0 / zz;
            const int   M2   = M + 20 + M/10;
            double fkp1 = 0.0, fk = 1e-30;
            for (int k = M2; k >= 1; --k) {
                double fkm1 = 2.0 * (double)k * inv * fk - fkp1;
                fkp1 = fk; fk = fkm1;
                const int idx = k - 1;
                if (idx <= M) fd[idx] = fk;
            }
            double S = fd[0];
            for (int idx = 2; idx <= M; idx += 2) S += 2.0 * fd[idx];
            Ssh = S;
        }
        for (int k = lane; k <= M; k += 64) jlf[k] = (float)(fd[k] / Ssh);
    }

    // ---- folded REAL coefficients of 2*xhat ----
    const float two_rho = 2.0f / rhoE;
    float dg2[8];
    #pragma unroll
    for (int r = 0; r < 8; ++r) dg2[r] = (Dd[r] - c0) * two_rho;
    float cx2[6];
    #pragma unroll
    for (int q = 0; q < 6; ++q) cx2[q] = ms[5 - q] * halfw * two_rho;
    float in2[3];
    #pragma unroll
    for (int p = 0; p < 3; ++p) in2[p] = ms[8 - p] * halfw * two_rho;
    const int bpaddr = (lane ^ 32) << 2;

    // ---- Chebyshev recurrence (REAL vectors) ----
    float p0[8], p1[8], accr[8], acci[8];
    #pragma unroll
    for (int r = 0; r < 8; ++r) { p0[r] = 0.f; p1[r] = 0.f; acci[r] = 0.f; }
    p0[0] = (lane == 0) ? 1.f : 0.f;

    const float J0 = jlf[0];
    #pragma unroll
    for (int r = 0; r < 8; ++r) accr[r] = J0 * p0[r];

    MV(p1, p0);
    #pragma unroll
    for (int r = 0; r < 8; ++r) p1[r] *= 0.5f;
    { const float c1 = 2.0f * jlf[1];
      #pragma unroll
      for (int r = 0; r < 8; ++r) acci[r] -= c1 * p1[r]; }

    int k = 2;
    while (k <= M) {
        MV(p0, p1);
        COEF(p0, k);
        ++k;
        if (k > M) break;
        MV(p1, p0);
        COEF(p1, k);
        ++k;
    }

    // ---- undo gauge + shift: psi_s = e^{-i(t c0 + phi n1(s))} chi_s ----
    const float base = t * c0;
    const float pcl  = (float)__popc(lane);
    #pragma unroll
    for (int r = 0; r < 8; ++r) {
        const float beta = base + phi * (pcl + (float)__popc(r));
        float sb, cbta;
        __sincosf(beta, &sb, &cbta);
        out[b*NST + (lane << 3) + r] = accr[r]*cbta + acci[r]*sb;
    }
}

extern "C" void kernel_launch(void* const* d_in, const int* in_sizes, int n_in,
                              void* d_out, int out_size, void* d_ws, size_t ws_size,
                              hipStream_t stream) {
    // Size-keyed input routing (pairwise-distinct element counts):
    //   x:16384  mask:576  adj:81  W1:33280  b1:130  W2:520  b2:4
    const float *x = nullptr, *msk = nullptr, *adj = nullptr,
                *W1 = nullptr, *b1 = nullptr, *W2 = nullptr, *b2 = nullptr;
    for (int i = 0; i < n_in; ++i) {
        const float* p = (const float*)d_in[i];
        switch (in_sizes[i]) {
            case 16384: x   = p; break;
            case 576:   msk = p; break;
            case 81:    adj = p; break;
            case 33280: W1  = p; break;
            case 130:   b1  = p; break;
            case 520:   W2  = p; break;
            case 4:     b2  = p; break;
            default: break;
        }
    }
    fused_kernel<<<NBATCH, 256, 0, stream>>>(x, msk, adj, W1, b1, W2, b2,
                                             (float*)d_out);
}